// Round 1
// baseline (349.933 us; speedup 1.0000x reference)
//
#include <hip/hip_runtime.h>
#include <math.h>

#define DIM 96
#define NE 6
#define NB 8
#define H 192
#define W 192
#define HW (H * W)

// ---------------- Kernel A: global max+mean pool per (b,c) ----------------
__global__ __launch_bounds__(256) void pool_kernel(const float* __restrict__ x,
                                                   float* __restrict__ pooled) {
    int bc = blockIdx.x;  // 0 .. NB*DIM-1
    const float4* xp = (const float4*)(x + (size_t)bc * HW);
    int tid = threadIdx.x;
    float vmax = -INFINITY, vsum = 0.f;
    for (int i = tid; i < HW / 4; i += 256) {
        float4 v = xp[i];
        vmax = fmaxf(vmax, fmaxf(fmaxf(v.x, v.y), fmaxf(v.z, v.w)));
        vsum += v.x + v.y + v.z + v.w;
    }
    for (int off = 32; off > 0; off >>= 1) {
        vmax = fmaxf(vmax, __shfl_down(vmax, off, 64));
        vsum += __shfl_down(vsum, off, 64);
    }
    __shared__ float smax[4], ssum[4];
    int wave = tid >> 6;
    if ((tid & 63) == 0) { smax[wave] = vmax; ssum[wave] = vsum; }
    __syncthreads();
    if (tid == 0) {
        float m = smax[0], s = ssum[0];
        for (int w = 1; w < 4; ++w) { m = fmaxf(m, smax[w]); s += ssum[w]; }
        pooled[bc] = m + s * (1.0f / (float)HW);
    }
}

// ---------------- Kernel B: gate (tiny) ----------------
__global__ void gate_kernel(const float* __restrict__ pooled,
                            const float* __restrict__ w_fc0, const float* __restrict__ b_fc0,
                            const float* __restrict__ w_fc1, const float* __restrict__ b_fc1,
                            float* __restrict__ cof) {
    int b = threadIdx.x;
    if (b >= NB) return;
    const float* p = pooled + b * DIM;
    float g[NE], noise[NE];
    for (int e = 0; e < NE; ++e) {
        float z1 = b_fc1[e], z0 = b_fc0[e];
        for (int i = 0; i < DIM; ++i) {
            float pi = p[i];
            z1 += pi * w_fc1[e * DIM + i];
            z0 += pi * w_fc0[e * DIM + i];
        }
        g[e] = (z1 > 0.f) ? z1 : 0.2f * z1;           // leaky_relu 0.2
        noise[e] = (z0 > 20.f) ? z0 : log1pf(expf(z0));  // softplus
    }
    float mu = 0.f;
    for (int e = 0; e < NE; ++e) mu += noise[e];
    mu *= (1.0f / NE);
    float var = 0.f;
    for (int e = 0; e < NE; ++e) { float d = noise[e] - mu; var += d * d; }
    var *= (1.0f / (NE - 1));                          // ddof=1 (torch.std unbiased)
    float sd = sqrtf(var);
    float scores[NE];
    for (int e = 0; e < NE; ++e) scores[e] = g[e] + (noise[e] - mu) / sd;

    bool chosen[NE] = {false, false, false, false, false, false};
    for (int k = 0; k < 3; ++k) {                      // top-3, ties -> lowest index
        float best = -INFINITY; int bi = -1;
        for (int e = 0; e < NE; ++e)
            if (!chosen[e] && scores[e] > best) { best = scores[e]; bi = e; }
        chosen[bi] = true;
    }
    float m = -INFINITY;
    for (int e = 0; e < NE; ++e) if (chosen[e]) m = fmaxf(m, g[e]);
    float s = 0.f;
    for (int e = 0; e < NE; ++e) if (chosen[e]) s += expf(g[e] - m);
    float inv = 1.0f / s;
    for (int e = 0; e < NE; ++e)
        cof[b * NE + e] = chosen[e] ? expf(g[e] - m) * inv : 0.f;
}

// ---------------- Kernel C: fused top-k expert dwconv-relu-dwconv ----------------
#define TX 64
#define TY 32
#define IX (TX + 4)   // 68  (input tile + 2-halo)
#define IY (TY + 4)   // 36
#define YX (TX + 2)   // 66  (conv1 output tile + 1-halo)
#define YY (TY + 2)   // 34

__global__ __launch_bounds__(256) void moe_kernel(const float* __restrict__ x,
                                                  const float* __restrict__ ew1,
                                                  const float* __restrict__ eb1,
                                                  const float* __restrict__ ew2,
                                                  const float* __restrict__ eb2,
                                                  const float* __restrict__ cof,
                                                  float* __restrict__ out) {
    __shared__ float xs[IY][IX];
    __shared__ float ys[YY][YX];
    const int tile = blockIdx.x;                 // 0..17 (3 x-tiles * 6 y-tiles)
    const int c = blockIdx.y;
    const int b = blockIdx.z;
    const int tx0 = (tile % (W / TX)) * TX;
    const int ty0 = (tile / (W / TX)) * TY;
    const int tid = threadIdx.x;

    const float* xp = x + ((size_t)(b * DIM + c)) * HW;

    // stage x tile with 2-halo, zero padding outside image
    for (int i = tid; i < IY * IX; i += 256) {
        int r = i / IX, cc = i - r * IX;
        int gh = ty0 + r - 2, gw = tx0 + cc - 2;
        float v = 0.f;
        if (gh >= 0 && gh < H && gw >= 0 && gw < W) v = xp[gh * W + gw];
        xs[r][cc] = v;
    }

    float acc[TY / 4];
    #pragma unroll
    for (int i = 0; i < TY / 4; ++i) acc[i] = 0.f;
    const int tx = tid & 63;
    const int ty_base = tid >> 6;  // 0..3

    for (int e = 0; e < NE; ++e) {
        float ce = cof[b * NE + e];      // uniform across block -> uniform branch
        if (ce == 0.f) continue;
        const float* w1 = ew1 + (size_t)(e * DIM + c) * 9;
        const float* w2 = ew2 + (size_t)(e * DIM + c) * 9;
        float w1r[9], w2r[9];
        #pragma unroll
        for (int k = 0; k < 9; ++k) { w1r[k] = w1[k]; w2r[k] = w2[k]; }
        const float bb1 = eb1[e * DIM + c];
        const float bb2 = eb2[e * DIM + c];

        __syncthreads();   // xs ready (1st iter) / prev conv2 reads of ys done
        // conv1 + bias + relu into ys; positions outside the image are ZERO
        // (conv2's zero-padding sees 0, NOT conv1 evaluated on padded x)
        for (int i = tid; i < YY * YX; i += 256) {
            int r = i / YX, cc = i - r * YX;
            int gh = ty0 + r - 1, gw = tx0 + cc - 1;
            float v = 0.f;
            if (gh >= 0 && gh < H && gw >= 0 && gw < W) {
                float s = bb1;
                s += w1r[0] * xs[r][cc]     + w1r[1] * xs[r][cc + 1]     + w1r[2] * xs[r][cc + 2];
                s += w1r[3] * xs[r + 1][cc] + w1r[4] * xs[r + 1][cc + 1] + w1r[5] * xs[r + 1][cc + 2];
                s += w1r[6] * xs[r + 2][cc] + w1r[7] * xs[r + 2][cc + 1] + w1r[8] * xs[r + 2][cc + 2];
                v = fmaxf(s, 0.f);
            }
            ys[r][cc] = v;
        }
        __syncthreads();
        // conv2 + bias, weighted accumulate
        #pragma unroll
        for (int i = 0; i < TY / 4; ++i) {
            int oy = ty_base + 4 * i;
            float s = bb2;
            s += w2r[0] * ys[oy][tx]     + w2r[1] * ys[oy][tx + 1]     + w2r[2] * ys[oy][tx + 2];
            s += w2r[3] * ys[oy + 1][tx] + w2r[4] * ys[oy + 1][tx + 1] + w2r[5] * ys[oy + 1][tx + 2];
            s += w2r[6] * ys[oy + 2][tx] + w2r[7] * ys[oy + 2][tx + 1] + w2r[8] * ys[oy + 2][tx + 2];
            acc[i] += ce * s;
        }
    }

    float* op = out + ((size_t)(b * DIM + c)) * HW;
    #pragma unroll
    for (int i = 0; i < TY / 4; ++i) {
        int oy = ty_base + 4 * i;
        op[(ty0 + oy) * W + tx0 + tx] = acc[i];
    }
}

extern "C" void kernel_launch(void* const* d_in, const int* in_sizes, int n_in,
                              void* d_out, int out_size, void* d_ws, size_t ws_size,
                              hipStream_t stream) {
    const float* x     = (const float*)d_in[0];
    const float* w_fc0 = (const float*)d_in[1];
    const float* b_fc0 = (const float*)d_in[2];
    const float* w_fc1 = (const float*)d_in[3];
    const float* b_fc1 = (const float*)d_in[4];
    const float* ew1   = (const float*)d_in[5];
    const float* eb1   = (const float*)d_in[6];
    const float* ew2   = (const float*)d_in[7];
    const float* eb2   = (const float*)d_in[8];
    float* out = (float*)d_out;

    float* pooled = (float*)d_ws;            // NB*DIM = 768 floats
    float* cof    = pooled + NB * DIM;       // NB*NE  = 48 floats

    pool_kernel<<<NB * DIM, 256, 0, stream>>>(x, pooled);
    gate_kernel<<<1, 64, 0, stream>>>(pooled, w_fc0, b_fc0, w_fc1, b_fc1, cof);
    dim3 grid((W / TX) * (H / TY), DIM, NB);  // (18, 96, 8)
    moe_kernel<<<grid, 256, 0, stream>>>(x, ew1, eb1, ew2, eb2, cof, out);
}

// Round 2
// 280.095 us; speedup vs baseline: 1.2493x; 1.2493x over previous
//
#include <hip/hip_runtime.h>
#include <math.h>

#define DIM 96
#define NE 6
#define NB 8
#define H 192
#define W 192
#define HW (H * W)
#define NQ 4            // pool partial quarters
#define QF4 (HW / 4 / NQ)  // 2304 float4 per quarter

// ---------------- Kernel A: partial max+sum per (b,c,quarter) ----------------
__global__ __launch_bounds__(256) void pool_partial(const float* __restrict__ x,
                                                    float* __restrict__ pmax,
                                                    float* __restrict__ psum) {
    int bc = blockIdx.x;       // 0..767
    int q = blockIdx.y;        // 0..3
    const float4* xp = (const float4*)(x + (size_t)bc * HW) + q * QF4;
    int tid = threadIdx.x;
    float vmax = -INFINITY, vsum = 0.f;
    for (int i = tid; i < QF4; i += 256) {
        float4 v = xp[i];
        vmax = fmaxf(vmax, fmaxf(fmaxf(v.x, v.y), fmaxf(v.z, v.w)));
        vsum += v.x + v.y + v.z + v.w;
    }
    for (int off = 32; off; off >>= 1) {
        vmax = fmaxf(vmax, __shfl_down(vmax, off, 64));
        vsum += __shfl_down(vsum, off, 64);
    }
    __shared__ float smax[4], ssum[4];
    if ((tid & 63) == 0) { smax[tid >> 6] = vmax; ssum[tid >> 6] = vsum; }
    __syncthreads();
    if (tid == 0) {
        float m = smax[0], s = ssum[0];
        for (int w = 1; w < 4; ++w) { m = fmaxf(m, smax[w]); s += ssum[w]; }
        pmax[q * (NB * DIM) + bc] = m;
        psum[q * (NB * DIM) + bc] = s;
    }
}

// ---------------- Kernel B: gate (parallel dots from LDS) ----------------
__global__ __launch_bounds__(128) void gate_kernel(const float* __restrict__ pmax,
                                                   const float* __restrict__ psum,
                                                   const float* __restrict__ w_fc0,
                                                   const float* __restrict__ b_fc0,
                                                   const float* __restrict__ w_fc1,
                                                   const float* __restrict__ b_fc1,
                                                   float* __restrict__ cof) {
    __shared__ float sp[NB * DIM];       // pooled
    __shared__ float sw1[NE * DIM], sw0[NE * DIM];
    __shared__ float z1s[NB * NE], z0s[NB * NE];
    int tid = threadIdx.x;
    // merge pool partials -> pooled = max + mean
    for (int i = tid; i < NB * DIM; i += 128) {
        float m = pmax[i], s = psum[i];
        for (int q = 1; q < NQ; ++q) {
            m = fmaxf(m, pmax[q * (NB * DIM) + i]);
            s += psum[q * (NB * DIM) + i];
        }
        sp[i] = m + s * (1.0f / (float)HW);
    }
    for (int i = tid; i < NE * DIM; i += 128) {
        sw1[i] = w_fc1[i];
        sw0[i] = w_fc0[i];
    }
    __syncthreads();
    if (tid < 2 * NB * NE) {             // 96 threads: one dot each
        int pair = (tid < NB * NE) ? tid : tid - NB * NE;
        int b = pair / NE, e = pair - b * NE;
        const float* wp = ((tid < NB * NE) ? sw1 : sw0) + e * DIM;
        float z = (tid < NB * NE) ? b_fc1[e] : b_fc0[e];
        const float* pp = sp + b * DIM;
        for (int i = 0; i < DIM; ++i) z = fmaf(pp[i], wp[i], z);
        if (tid < NB * NE) z1s[pair] = z; else z0s[pair] = z;
    }
    __syncthreads();
    if (tid < NB) {
        int b = tid;
        float g[NE], noise[NE];
        for (int e = 0; e < NE; ++e) {
            float z1 = z1s[b * NE + e], z0 = z0s[b * NE + e];
            g[e] = (z1 > 0.f) ? z1 : 0.2f * z1;                 // leaky_relu 0.2
            noise[e] = (z0 > 20.f) ? z0 : log1pf(expf(z0));     // softplus
        }
        float mu = 0.f;
        for (int e = 0; e < NE; ++e) mu += noise[e];
        mu *= (1.0f / NE);
        float var = 0.f;
        for (int e = 0; e < NE; ++e) { float d = noise[e] - mu; var += d * d; }
        var *= (1.0f / (NE - 1));                               // ddof=1
        float sd = sqrtf(var);
        float scores[NE];
        for (int e = 0; e < NE; ++e) scores[e] = g[e] + (noise[e] - mu) / sd;
        bool chosen[NE] = {false, false, false, false, false, false};
        for (int k = 0; k < 3; ++k) {                           // top-3, ties -> lowest idx
            float best = -INFINITY; int bi = 0;
            for (int e = 0; e < NE; ++e)
                if (!chosen[e] && scores[e] > best) { best = scores[e]; bi = e; }
            chosen[bi] = true;
        }
        float m = -INFINITY;
        for (int e = 0; e < NE; ++e) if (chosen[e]) m = fmaxf(m, g[e]);
        float s = 0.f;
        for (int e = 0; e < NE; ++e) if (chosen[e]) s += expf(g[e] - m);
        float inv = 1.0f / s;
        for (int e = 0; e < NE; ++e)
            cof[b * NE + e] = chosen[e] ? expf(g[e] - m) * inv : 0.f;
    }
}

// ---------------- Kernel C: fused top-k expert dwconv-relu-dwconv ----------------
#define TX 64
#define TY 32
#define IX (TX + 4)   // 68
#define IY (TY + 4)   // 36
#define YX (TX + 2)   // 66
#define YY (TY + 2)   // 34

__global__ __launch_bounds__(256) void moe_kernel(const float* __restrict__ x,
                                                  const float* __restrict__ ew1,
                                                  const float* __restrict__ eb1,
                                                  const float* __restrict__ ew2,
                                                  const float* __restrict__ eb2,
                                                  const float* __restrict__ cof,
                                                  float* __restrict__ out) {
    __shared__ float xs[IY][IX];
    __shared__ float ys[YY][YX];
    const int tile = blockIdx.x;                 // 0..17
    const int c = blockIdx.y;
    const int b = blockIdx.z;
    const int tx0 = (tile % (W / TX)) * TX;
    const int ty0 = (tile / (W / TX)) * TY;
    const int tid = threadIdx.x;
    const int tx = tid & 63;
    const int wv = (tid >> 6) & 3;

    const float* xp = x + ((size_t)(b * DIM + c)) * HW;

    // ---- stage x tile + 2-halo (wave-per-row; bounds mostly wave-uniform) ----
    #pragma unroll
    for (int rr = 0; rr < 9; ++rr) {
        int r = wv + rr * 4;                     // 0..35
        int gh = ty0 + r - 2;
        int gw = tx0 + tx - 2;
        float v = 0.f, v2 = 0.f;
        if (gh >= 0 && gh < H) {
            if (gw >= 0 && gw < W) v = xp[gh * W + gw];
            int gw2 = gw + 64;
            if (tx < 4 && gw2 < W) v2 = xp[gh * W + gw2];
        }
        xs[r][tx] = v;
        if (tx < 4) xs[r][tx + 64] = v2;
    }

    // border flags (uniform): out-of-image ys rows/cols must be ZERO
    const bool topB = (ty0 == 0), botB = (ty0 == H - TY);
    const bool leftB = (tx0 == 0), rightB = (tx0 == W - TX);
    const int zr0 = topB ? 0 : -1;
    const int zr1 = botB ? (YY - 1) : -1;
    const bool lzero = leftB && (tx == 0);       // ys col 0 out of image

    float acc[8];
    #pragma unroll
    for (int i = 0; i < 8; ++i) acc[i] = 0.f;

    // conv1: wave w owns 9 contiguous rows, starts {0,9,17,25} (dup rows benign)
    const int rs = wv * 8 + (wv ? 1 : 0);
    // conv2: wave w owns output rows [8w, 8w+8)
    const int r2 = wv * 8;

    for (int e = 0; e < NE; ++e) {
        float ce = cof[b * NE + e];              // uniform -> uniform branch
        if (ce == 0.f) continue;
        const float* w1 = ew1 + (size_t)(e * DIM + c) * 9;
        const float* w2 = ew2 + (size_t)(e * DIM + c) * 9;
        float w1r[9], w2r[9];
        #pragma unroll
        for (int k = 0; k < 9; ++k) { w1r[k] = w1[k]; w2r[k] = w2[k]; }
        const float bb1 = eb1[e * DIM + c];
        const float bb2 = eb2[e * DIM + c];

        __syncthreads();   // xs ready / previous conv2 reads of ys done

        // ---- conv1 + bias + relu, sliding 3-row window ----
        {
            float a0 = xs[rs][tx], a1 = xs[rs][tx + 1], a2 = xs[rs][tx + 2];
            float b0 = xs[rs + 1][tx], b1 = xs[rs + 1][tx + 1], b2 = xs[rs + 1][tx + 2];
            #pragma unroll
            for (int j = 0; j < 9; ++j) {
                int r = rs + j;
                float c0 = xs[r + 2][tx], c1 = xs[r + 2][tx + 1], c2 = xs[r + 2][tx + 2];
                float s = fmaf(w1r[0], a0, fmaf(w1r[1], a1, fmaf(w1r[2], a2, bb1)));
                s = fmaf(w1r[3], b0, fmaf(w1r[4], b1, fmaf(w1r[5], b2, s)));
                s = fmaf(w1r[6], c0, fmaf(w1r[7], c1, fmaf(w1r[8], c2, s)));
                float v = fmaxf(s, 0.f);
                if (r == zr0 || r == zr1 || lzero) v = 0.f;
                ys[r][tx] = v;
                a0 = b0; a1 = b1; a2 = b2;
                b0 = c0; b1 = c1; b2 = c2;
            }
        }
        // extra ys columns 64,65 (halo): threads 0..67
        if (tid < 2 * YY) {
            int r = tid >> 1;
            int cc = 64 + (tid & 1);
            float s = bb1;
            #pragma unroll
            for (int dr = 0; dr < 3; ++dr)
                #pragma unroll
                for (int dc = 0; dc < 3; ++dc)
                    s = fmaf(w1r[dr * 3 + dc], xs[r + dr][cc + dc], s);
            float v = fmaxf(s, 0.f);
            if (r == zr0 || r == zr1 || (rightB && cc == YX - 1)) v = 0.f;
            ys[r][cc] = v;
        }
        __syncthreads();

        // ---- conv2 + bias, sliding window over contiguous 8-row band ----
        {
            float p0 = ys[r2][tx], p1 = ys[r2][tx + 1], p2 = ys[r2][tx + 2];
            float q0 = ys[r2 + 1][tx], q1 = ys[r2 + 1][tx + 1], q2 = ys[r2 + 1][tx + 2];
            #pragma unroll
            for (int j = 0; j < 8; ++j) {
                float u0 = ys[r2 + j + 2][tx], u1 = ys[r2 + j + 2][tx + 1], u2 = ys[r2 + j + 2][tx + 2];
                float s = fmaf(w2r[0], p0, fmaf(w2r[1], p1, fmaf(w2r[2], p2, bb2)));
                s = fmaf(w2r[3], q0, fmaf(w2r[4], q1, fmaf(w2r[5], q2, s)));
                s = fmaf(w2r[6], u0, fmaf(w2r[7], u1, fmaf(w2r[8], u2, s)));
                acc[j] = fmaf(ce, s, acc[j]);
                p0 = q0; p1 = q1; p2 = q2;
                q0 = u0; q1 = u1; q2 = u2;
            }
        }
    }

    float* op = out + ((size_t)(b * DIM + c)) * HW + (size_t)(ty0 + r2) * W + tx0 + tx;
    #pragma unroll
    for (int j = 0; j < 8; ++j) op[j * W] = acc[j];
}

extern "C" void kernel_launch(void* const* d_in, const int* in_sizes, int n_in,
                              void* d_out, int out_size, void* d_ws, size_t ws_size,
                              hipStream_t stream) {
    const float* x     = (const float*)d_in[0];
    const float* w_fc0 = (const float*)d_in[1];
    const float* b_fc0 = (const float*)d_in[2];
    const float* w_fc1 = (const float*)d_in[3];
    const float* b_fc1 = (const float*)d_in[4];
    const float* ew1   = (const float*)d_in[5];
    const float* eb1   = (const float*)d_in[6];
    const float* ew2   = (const float*)d_in[7];
    const float* eb2   = (const float*)d_in[8];
    float* out = (float*)d_out;

    float* pmax = (float*)d_ws;                       // NQ*768
    float* psum = pmax + NQ * NB * DIM;               // NQ*768
    float* cof  = psum + NQ * NB * DIM;               // 48

    dim3 pg(NB * DIM, NQ);
    pool_partial<<<pg, 256, 0, stream>>>(x, pmax, psum);
    gate_kernel<<<1, 128, 0, stream>>>(pmax, psum, w_fc0, b_fc0, w_fc1, b_fc1, cof);
    dim3 grid((W / TX) * (H / TY), DIM, NB);          // (18, 96, 8)
    moe_kernel<<<grid, 256, 0, stream>>>(x, ew1, eb1, ew2, eb2, cof, out);
}